// Round 1
// baseline (292.066 us; speedup 1.0000x reference)
//
#include <hip/hip_runtime.h>
#include <math.h>

#define Bn 2
#define DM 192
#define DI 384
#define DS 16
#define HH 64
#define WW 64
#define HW 4096
#define ND 4

__device__ __forceinline__ float sigmoidf_(float x) {
    return 1.0f / (1.0f + __expf(-x));
}

// ---------------- K1: in_proj (1x1) + SiLU ----------------
// grid (16, 24, 2), block 256. Each thread: 16 output channels for one pixel.
__global__ __launch_bounds__(256) void k_inproj(const float* __restrict__ x,
                                                const float* __restrict__ w,
                                                float* __restrict__ hpre) {
    __shared__ float wl[16 * DM]; // 12 KB, 16 consecutive rows of in_proj_w
    int og = blockIdx.y, b = blockIdx.z;
    int p = blockIdx.x * 256 + threadIdx.x;
    for (int i = threadIdx.x; i < 16 * DM; i += 256)
        wl[i] = w[og * 16 * DM + i];
    __syncthreads();
    const float* xb = x + (size_t)b * DM * HW + p;
    float acc[16];
#pragma unroll
    for (int j = 0; j < 16; ++j) acc[j] = 0.f;
    for (int c = 0; c < DM; ++c) {
        float xv = xb[(size_t)c * HW];
#pragma unroll
        for (int j = 0; j < 16; ++j) acc[j] = fmaf(wl[j * DM + c], xv, acc[j]);
    }
    float* hb = hpre + (size_t)b * DI * HW + (size_t)(og * 16) * HW + p;
#pragma unroll
    for (int j = 0; j < 16; ++j) {
        float v = acc[j];
        hb[(size_t)j * HW] = v * (1.0f / (1.0f + __expf(-v)));
    }
}

// ---------------- K2: depthwise 3x3 conv + bias ----------------
// grid (16, 384, 2), block 256.
__global__ __launch_bounds__(256) void k_dwconv(const float* __restrict__ hpre,
                                                const float* __restrict__ w,
                                                const float* __restrict__ bias,
                                                float* __restrict__ h) {
    int c = blockIdx.y, b = blockIdx.z;
    int p = blockIdx.x * 256 + threadIdx.x;
    int i = p >> 6, j = p & 63;
    const float* wp = w + c * 9;
    const float* src = hpre + ((size_t)b * DI + c) * HW;
    float acc = bias[c];
#pragma unroll
    for (int di = -1; di <= 1; ++di) {
        int ii = i + di;
        if (ii < 0 || ii >= HH) continue;
#pragma unroll
        for (int dj = -1; dj <= 1; ++dj) {
            int jj = j + dj;
            if (jj < 0 || jj >= WW) continue;
            acc = fmaf(wp[(di + 1) * 3 + (dj + 1)], src[ii * WW + jj], acc);
        }
    }
    h[((size_t)b * DI + c) * HW + p] = acc;
}

// ---------------- K3: x_down -> xp transposed [b][p][s] ----------------
// grid 32, block 256. Each thread: one pixel, all 16 states.
__global__ __launch_bounds__(256) void k_xdown(const float* __restrict__ h,
                                               const float* __restrict__ w,
                                               float* __restrict__ xpt) {
    __shared__ float wl[DI * DS]; // transposed: wl[c*16+s] = w[s*DI+c], 24 KB
    for (int i = threadIdx.x; i < DI * DS; i += 256) {
        int c = i >> 4, s = i & 15;
        wl[i] = w[s * DI + c];
    }
    __syncthreads();
    int t = blockIdx.x * 256 + threadIdx.x; // 0..8191
    int b = t >> 12, p = t & 4095;
    const float* hb = h + (size_t)b * DI * HW + p;
    float acc[16];
#pragma unroll
    for (int s = 0; s < 16; ++s) acc[s] = 0.f;
    for (int c = 0; c < DI; ++c) {
        float hv = hb[(size_t)c * HW];
#pragma unroll
        for (int s = 0; s < 16; ++s) acc[s] = fmaf(wl[c * 16 + s], hv, acc[s]);
    }
    float* o = xpt + (size_t)t * 16;
#pragma unroll
    for (int s = 0; s < 16; ++s) o[s] = acc[s];
}

// ---------------- K4: fused gate-recurrent scan, all 4 directions ----------------
// grid (384, 2), block 256 (4 waves = 4 directions, lane = h).
__global__ __launch_bounds__(256) void k_scan(const float* __restrict__ h,
                                              const float* __restrict__ xpt,
                                              const float* __restrict__ wup,
                                              const float* __restrict__ lup,
                                              const float* __restrict__ uup,
                                              const float* __restrict__ dup,
                                              const float* __restrict__ mw,
                                              float* __restrict__ y) {
    int c = blockIdx.x, b = blockIdx.y;
    int tid = threadIdx.x;
    int d = tid >> 6, hl = tid & 63;

    __shared__ float htile[64][65];   // h tile for this (b,c), padded
    __shared__ float accs[64][65];    // merged output tile, padded
    __shared__ float xpcol[16][66];   // xp column [s][h], padded
    __shared__ float colm[4][64];     // per-direction column contributions

    const float* hb = h + ((size_t)b * DI + c) * HW;
    for (int i = tid; i < HW; i += 256) htile[i >> 6][i & 63] = hb[i];

    // gate/proj weight rows for (d, c): kept in registers (static indexing only)
    float w1[16], w2[16], w3[16], wL[16], wU[16], wD[16];
    {
        int row = d * DI + c;
        const float* p1 = wup + (size_t)row * DS;
        const float* p2 = wup + (size_t)(4 * DI + row) * DS;
        const float* p3 = wup + (size_t)(8 * DI + row) * DS;
        const float* pL = lup + (size_t)row * DS;
        const float* pU = uup + (size_t)row * DS;
        const float* pD = dup + (size_t)row * DS;
#pragma unroll
        for (int s = 0; s < 16; ++s) {
            w1[s] = p1[s]; w2[s] = p2[s]; w3[s] = p3[s];
            wL[s] = pL[s]; wU[s] = pU[s]; wD[s] = pD[s];
        }
    }
    float md = mw[d];
    const float* xpb = xpt + (size_t)b * HW * DS;

    float hprev = 0.f;
    __syncthreads(); // htile ready

    for (int w = 0; w < 64; ++w) {
        // stage xp column w into LDS: xpcol[s][hh]
        for (int i = tid; i < 1024; i += 256) {
            int hh = i >> 4, s = i & 15;
            xpcol[s][hh] = xpb[(size_t)(hh * 64 + w) * DS + s];
        }
        __syncthreads(); // xpcol ready; also protects colm from previous iter

        float g1 = 0, g2 = 0, g3 = 0, L = 0, U = 0, Dv = 0;
#pragma unroll
        for (int s = 0; s < 16; ++s) {
            float xv = xpcol[s][hl];
            g1 = fmaf(w1[s], xv, g1);
            g2 = fmaf(w2[s], xv, g2);
            g3 = fmaf(w3[s], xv, g3);
            L  = fmaf(wL[s], xv, L);
            U  = fmaf(wU[s], xv, U);
            Dv = fmaf(wD[s], xv, Dv);
        }
        g1 = sigmoidf_(g1); g2 = sigmoidf_(g2); g3 = sigmoidf_(g3);
        float ssum = (hl == 0) ? (g2 + g3) : (hl == 63) ? (g1 + g2) : (g1 + g2 + g3);
        ssum = fmaxf(ssum, 1e-7f);
        float inv = 1.0f / ssum;
        float n1 = g1 * inv, n2 = g2 * inv, n3 = g3 * inv;

        // X from direction-transformed h (all reads from LDS tile)
        float X;
        if (d == 0)      X = htile[hl][w];
        else if (d == 1) X = htile[w][hl];
        else if (d == 2) X = htile[hl][63 - w];
        else             X = htile[63 - w][hl];

        float up = __shfl_up(hprev, 1);
        float dn = __shfl_down(hprev, 1);
        if (hl == 0) up = 0.f;
        if (hl == 63) dn = 0.f;

        float hnew = fmaf(L, X, fmaf(n1, up, fmaf(n2, hprev, n3 * dn)));
        hprev = hnew;
        colm[d][hl] = md * (hnew * U + X * Dv);
        __syncthreads(); // colm complete for this column
        if (d == 0)
            accs[hl][w] = colm[0][hl] + colm[1][hl] + colm[2][hl] + colm[3][hl];
        // next iteration's first barrier protects colm/xpcol reuse
    }
    __syncthreads();
    float* yb = y + ((size_t)b * DI + c) * HW;
    for (int i = tid; i < HW; i += 256) yb[i] = accs[i >> 6][i & 63];
}

// ---------------- K5: LayerNorm2d over channels, in-place ----------------
// grid 32, block 256. Thread per pixel.
__global__ __launch_bounds__(256) void k_ln(float* __restrict__ y,
                                            const float* __restrict__ nw,
                                            const float* __restrict__ nb) {
    int t = blockIdx.x * 256 + threadIdx.x;
    int b = t >> 12, p = t & 4095;
    float* yb = y + (size_t)b * DI * HW + p;
    float s = 0.f, s2 = 0.f;
    for (int c = 0; c < DI; ++c) {
        float v = yb[(size_t)c * HW];
        s += v;
        s2 = fmaf(v, v, s2);
    }
    float mu = s * (1.0f / DI);
    float var = s2 * (1.0f / DI) - mu * mu;
    float inv = rsqrtf(var + 1e-5f);
    for (int c = 0; c < DI; ++c) {
        float v = (yb[(size_t)c * HW] - mu) * inv;
        yb[(size_t)c * HW] = fmaf(v, nw[c], nb[c]);
    }
}

// ---------------- K6: GRN per-channel sumsq -> Gx ----------------
// grid (384, 2), block 256.
__global__ __launch_bounds__(256) void k_grnsum(const float* __restrict__ y,
                                                float* __restrict__ gx) {
    int c = blockIdx.x, b = blockIdx.y;
    const float* yb = y + ((size_t)b * DI + c) * HW;
    float s = 0.f;
    for (int i = threadIdx.x; i < HW; i += 256) {
        float v = yb[i];
        s = fmaf(v, v, s);
    }
#pragma unroll
    for (int o = 32; o > 0; o >>= 1) s += __shfl_down(s, o);
    __shared__ float red[4];
    int wid = threadIdx.x >> 6;
    if ((threadIdx.x & 63) == 0) red[wid] = s;
    __syncthreads();
    if (threadIdx.x == 0) {
        gx[b * DI + c] = sqrtf(red[0] + red[1] + red[2] + red[3]);
    }
}

// ---------------- K7: GRN scale: sc = 1 + gamma * Gx/(mean+1e-6) ----------------
// grid 2, block 256.
__global__ __launch_bounds__(256) void k_grnscale(const float* __restrict__ gx,
                                                  const float* __restrict__ gamma,
                                                  float* __restrict__ sc) {
    int b = blockIdx.x;
    const float* g = gx + b * DI;
    float s = 0.f;
    for (int c = threadIdx.x; c < DI; c += 256) s += g[c];
#pragma unroll
    for (int o = 32; o > 0; o >>= 1) s += __shfl_down(s, o);
    __shared__ float red[4];
    __shared__ float meanv;
    int wid = threadIdx.x >> 6;
    if ((threadIdx.x & 63) == 0) red[wid] = s;
    __syncthreads();
    if (threadIdx.x == 0) meanv = (red[0] + red[1] + red[2] + red[3]) * (1.0f / DI);
    __syncthreads();
    float m = meanv;
    for (int c = threadIdx.x; c < DI; c += 256)
        sc[b * DI + c] = 1.0f + gamma[c] * (g[c] / (m + 1e-6f));
}

// ---------------- K8: out_proj GEMM fused with GRN scale/shift ----------------
// grid (16, 12, 2), block 256. Each thread: 16 output channels for one pixel.
__global__ __launch_bounds__(256) void k_outproj(const float* __restrict__ y,
                                                 const float* __restrict__ w,
                                                 const float* __restrict__ sc_all,
                                                 const float* __restrict__ beta,
                                                 float* __restrict__ out) {
    __shared__ float wl[16 * DI]; // 24 KB
    __shared__ float scl[DI], btl[DI];
    int og = blockIdx.y, b = blockIdx.z;
    int p = blockIdx.x * 256 + threadIdx.x;
    for (int i = threadIdx.x; i < 16 * DI; i += 256) wl[i] = w[og * 16 * DI + i];
    for (int i = threadIdx.x; i < DI; i += 256) {
        scl[i] = sc_all[b * DI + i];
        btl[i] = beta[i];
    }
    __syncthreads();
    const float* yb = y + (size_t)b * DI * HW + p;
    float acc[16];
#pragma unroll
    for (int j = 0; j < 16; ++j) acc[j] = 0.f;
    for (int c = 0; c < DI; ++c) {
        float v = fmaf(yb[(size_t)c * HW], scl[c], btl[c]);
#pragma unroll
        for (int j = 0; j < 16; ++j) acc[j] = fmaf(wl[j * DI + c], v, acc[j]);
    }
    float* ob = out + (size_t)b * DM * HW + (size_t)(og * 16) * HW + p;
#pragma unroll
    for (int j = 0; j < 16; ++j) ob[(size_t)j * HW] = acc[j];
}

extern "C" void kernel_launch(void* const* d_in, const int* in_sizes, int n_in,
                              void* d_out, int out_size, void* d_ws, size_t ws_size,
                              hipStream_t stream) {
    (void)in_sizes; (void)n_in; (void)out_size; (void)ws_size;
    const float* x          = (const float*)d_in[0];
    const float* in_proj_w  = (const float*)d_in[1];
    const float* dwconv_w   = (const float*)d_in[2];
    const float* dwconv_b   = (const float*)d_in[3];
    const float* x_down_w   = (const float*)d_in[4];
    const float* w_up_w     = (const float*)d_in[5];
    const float* l_up_w     = (const float*)d_in[6];
    const float* u_up_w     = (const float*)d_in[7];
    const float* d_up_w     = (const float*)d_in[8];
    const float* m_w        = (const float*)d_in[9];
    const float* grn_gamma  = (const float*)d_in[10];
    const float* grn_beta   = (const float*)d_in[11];
    const float* norm_w     = (const float*)d_in[12];
    const float* norm_b     = (const float*)d_in[13];
    const float* out_proj_w = (const float*)d_in[14];

    float* ws = (float*)d_ws;
    const size_t NBIG = (size_t)Bn * DI * HW; // 3,145,728 floats
    float* hpre = ws;                  // [B,DI,H,W], later reused as y
    float* hbuf = ws + NBIG;           // [B,DI,H,W] post-dwconv
    float* xpt  = ws + 2 * NBIG;       // [B,HW,DS]
    float* gx   = ws + 2 * NBIG + (size_t)Bn * HW * DS; // [B,DI]
    float* sc   = gx + Bn * DI;        // [B,DI]
    float* y    = hpre;                // alias: hpre dead after dwconv

    k_inproj<<<dim3(16, 24, 2), 256, 0, stream>>>(x, in_proj_w, hpre);
    k_dwconv<<<dim3(16, DI, Bn), 256, 0, stream>>>(hpre, dwconv_w, dwconv_b, hbuf);
    k_xdown<<<dim3(32), 256, 0, stream>>>(hbuf, x_down_w, xpt);
    k_scan<<<dim3(DI, Bn), 256, 0, stream>>>(hbuf, xpt, w_up_w, l_up_w, u_up_w,
                                             d_up_w, m_w, y);
    k_ln<<<dim3(32), 256, 0, stream>>>(y, norm_w, norm_b);
    k_grnsum<<<dim3(DI, Bn), 256, 0, stream>>>(y, gx);
    k_grnscale<<<dim3(Bn), 256, 0, stream>>>(gx, grn_gamma, sc);
    k_outproj<<<dim3(16, 12, 2), 256, 0, stream>>>(y, out_proj_w, sc, grn_beta,
                                                   (float*)d_out);
}

// Round 2
// 227.158 us; speedup vs baseline: 1.2857x; 1.2857x over previous
//
#include <hip/hip_runtime.h>
#include <math.h>

#define Bn 2
#define DM 192
#define DI 384
#define DS 16
#define HH 64
#define WW 64
#define HW 4096
#define ND 4

__device__ __forceinline__ float sigmoidf_(float x) {
    return 1.0f / (1.0f + __expf(-x));
}

// ---------------- K1: in_proj (1x1) + SiLU ----------------
// grid (16, 24, 2), block 256. Thread: 16 output channels for one pixel.
// Weights read via wave-uniform addresses -> s_load (scalar pipe), no LDS.
__global__ __launch_bounds__(256) void k_inproj(const float* __restrict__ x,
                                                const float* __restrict__ w,
                                                float* __restrict__ hpre) {
    int og = blockIdx.y, b = blockIdx.z;
    int p = blockIdx.x * 256 + threadIdx.x;
    const float* wr = w + (size_t)og * 16 * DM;
    const float* xb = x + (size_t)b * DM * HW + p;
    float acc[16];
#pragma unroll
    for (int j = 0; j < 16; ++j) acc[j] = 0.f;
    for (int c = 0; c < DM; c += 4) {
        float x0 = xb[(size_t)(c + 0) * HW];
        float x1 = xb[(size_t)(c + 1) * HW];
        float x2 = xb[(size_t)(c + 2) * HW];
        float x3 = xb[(size_t)(c + 3) * HW];
#pragma unroll
        for (int j = 0; j < 16; ++j) {
            const float* wj = wr + j * DM + c;  // wave-uniform -> SGPR
            acc[j] = fmaf(wj[0], x0, fmaf(wj[1], x1, fmaf(wj[2], x2, fmaf(wj[3], x3, acc[j]))));
        }
    }
    float* hb = hpre + (size_t)b * DI * HW + (size_t)(og * 16) * HW + p;
#pragma unroll
    for (int j = 0; j < 16; ++j) {
        float v = acc[j];
        hb[(size_t)j * HW] = v * (1.0f / (1.0f + __expf(-v)));
    }
}

// ---------------- K2: depthwise 3x3 conv + bias ----------------
// grid (16, 384, 2), block 256.
__global__ __launch_bounds__(256) void k_dwconv(const float* __restrict__ hpre,
                                                const float* __restrict__ w,
                                                const float* __restrict__ bias,
                                                float* __restrict__ h) {
    int c = blockIdx.y, b = blockIdx.z;
    int p = blockIdx.x * 256 + threadIdx.x;
    int i = p >> 6, j = p & 63;
    const float* wp = w + c * 9;
    const float* src = hpre + ((size_t)b * DI + c) * HW;
    float acc = bias[c];
#pragma unroll
    for (int di = -1; di <= 1; ++di) {
        int ii = i + di;
        if (ii < 0 || ii >= HH) continue;
#pragma unroll
        for (int dj = -1; dj <= 1; ++dj) {
            int jj = j + dj;
            if (jj < 0 || jj >= WW) continue;
            acc = fmaf(wp[(di + 1) * 3 + (dj + 1)], src[ii * WW + jj], acc);
        }
    }
    h[((size_t)b * DI + c) * HW + p] = acc;
}

// ---------------- K3: x_down -> xp transposed [b][p][s] ----------------
// grid (32, 4), block 256. Thread: one pixel, 4 of 16 states (s-split for occupancy).
__global__ __launch_bounds__(256) void k_xdown(const float* __restrict__ h,
                                               const float* __restrict__ w,
                                               float* __restrict__ xpt) {
    int sq = blockIdx.y;  // state quad: s in [4*sq, 4*sq+4)
    int t = blockIdx.x * 256 + threadIdx.x;  // 0..8191
    int b = t >> 12, p = t & 4095;
    const float* hb = h + (size_t)b * DI * HW + p;
    const float* w0 = w + (size_t)(4 * sq + 0) * DI;
    const float* w1 = w + (size_t)(4 * sq + 1) * DI;
    const float* w2 = w + (size_t)(4 * sq + 2) * DI;
    const float* w3 = w + (size_t)(4 * sq + 3) * DI;
    float a0 = 0.f, a1 = 0.f, a2 = 0.f, a3 = 0.f;
#pragma unroll 16
    for (int c = 0; c < DI; ++c) {
        float hv = hb[(size_t)c * HW];
        a0 = fmaf(w0[c], hv, a0);
        a1 = fmaf(w1[c], hv, a1);
        a2 = fmaf(w2[c], hv, a2);
        a3 = fmaf(w3[c], hv, a3);
    }
    float4 r = {a0, a1, a2, a3};
    *reinterpret_cast<float4*>(xpt + (size_t)t * 16 + 4 * sq) = r;
}

// ---------------- K4: fused gate-recurrent scan, all 4 directions ----------------
// grid (384, 2), block 256 (4 waves = 4 directions, lane = h).
// Zero in-loop barriers: xp read per-lane from global (prefetched), direction
// merge via LDS atomicAdd (ds_add_f32).
__global__ __launch_bounds__(256) void k_scan(const float* __restrict__ h,
                                              const float* __restrict__ xpt,
                                              const float* __restrict__ wup,
                                              const float* __restrict__ lup,
                                              const float* __restrict__ uup,
                                              const float* __restrict__ dup,
                                              const float* __restrict__ mw,
                                              float* __restrict__ y) {
    int c = blockIdx.x, b = blockIdx.y;
    int tid = threadIdx.x;
    int d = tid >> 6, hl = tid & 63;

    __shared__ float htile[64][65];  // h tile, padded (column reads conflict-free)
    __shared__ float acc[64][65];    // merged output tile

    const float* hb = h + ((size_t)b * DI + c) * HW;
    for (int i = tid; i < HW; i += 256) {
        htile[i >> 6][i & 63] = hb[i];
        acc[i >> 6][i & 63] = 0.f;
    }

    // gate/proj weight rows for (d, c): wave-uniform -> compiler puts in SGPRs
    int row = d * DI + c;
    const float* p1 = wup + (size_t)row * DS;
    const float* p2 = wup + (size_t)(4 * DI + row) * DS;
    const float* p3 = wup + (size_t)(8 * DI + row) * DS;
    const float* pL = lup + (size_t)row * DS;
    const float* pU = uup + (size_t)row * DS;
    const float* pD = dup + (size_t)row * DS;
    float w1[16], w2[16], w3[16], wL[16], wU[16], wD[16];
#pragma unroll
    for (int s = 0; s < 16; ++s) {
        w1[s] = p1[s]; w2[s] = p2[s]; w3[s] = p3[s];
        wL[s] = pL[s]; wU[s] = pU[s]; wD[s] = pD[s];
    }
    float md = mw[d];

    // per-lane xp pointer: xpt[b][hl*64 + w][0:16]
    const float4* xq = reinterpret_cast<const float4*>(
        xpt + ((size_t)b * HW + (size_t)hl * 64) * DS);

    // prefetch column 0
    float4 c0 = xq[0], c1 = xq[1], c2 = xq[2], c3 = xq[3];
    float hprev = 0.f;
    __syncthreads();  // htile + acc ready

    for (int w = 0; w < 64; ++w) {
        // prefetch next column (independent of recurrence)
        int nw = (w < 63) ? w + 1 : w;
        float4 n0 = xq[nw * 4 + 0], n1 = xq[nw * 4 + 1];
        float4 n2 = xq[nw * 4 + 2], n3 = xq[nw * 4 + 3];

        float xv[16] = {c0.x, c0.y, c0.z, c0.w, c1.x, c1.y, c1.z, c1.w,
                        c2.x, c2.y, c2.z, c2.w, c3.x, c3.y, c3.z, c3.w};
        float g1 = 0, g2 = 0, g3 = 0, L = 0, U = 0, Dv = 0;
#pragma unroll
        for (int s = 0; s < 16; ++s) {
            g1 = fmaf(w1[s], xv[s], g1);
            g2 = fmaf(w2[s], xv[s], g2);
            g3 = fmaf(w3[s], xv[s], g3);
            L  = fmaf(wL[s], xv[s], L);
            U  = fmaf(wU[s], xv[s], U);
            Dv = fmaf(wD[s], xv[s], Dv);
        }
        g1 = sigmoidf_(g1); g2 = sigmoidf_(g2); g3 = sigmoidf_(g3);
        float ssum = (hl == 0) ? (g2 + g3) : (hl == 63) ? (g1 + g2) : (g1 + g2 + g3);
        ssum = fmaxf(ssum, 1e-7f);
        float inv = 1.0f / ssum;
        float n1g = g1 * inv, n2g = g2 * inv, n3g = g3 * inv;

        // X from direction-transformed h (wave-uniform branch)
        float X;
        if (d == 0)      X = htile[hl][w];
        else if (d == 1) X = htile[w][hl];
        else if (d == 2) X = htile[hl][63 - w];
        else             X = htile[63 - w][hl];

        float up = __shfl_up(hprev, 1);
        float dn = __shfl_down(hprev, 1);
        if (hl == 0) up = 0.f;
        if (hl == 63) dn = 0.f;

        float hnew = fmaf(L, X, fmaf(n1g, up, fmaf(n2g, hprev, n3g * dn)));
        hprev = hnew;
        atomicAdd(&acc[hl][w], md * fmaf(hnew, U, X * Dv));

        c0 = n0; c1 = n1; c2 = n2; c3 = n3;
    }
    __syncthreads();
    float* yb = y + ((size_t)b * DI + c) * HW;
    for (int i = tid; i < HW; i += 256) yb[i] = acc[i >> 6][i & 63];
}

// ---------------- K5: LayerNorm2d over channels, in-place, single pass ----------------
// grid (256), block 256. Block: 32 pixels x 8 channel-chunks (48 channels each).
__global__ __launch_bounds__(256) void k_ln(float* __restrict__ y,
                                            const float* __restrict__ nw,
                                            const float* __restrict__ nb) {
    int lpx = threadIdx.x & 31, chunk = threadIdx.x >> 5;
    int gp = blockIdx.x * 32 + lpx;  // global pixel 0..8191
    int b = gp >> 12, p = gp & 4095;
    float* yb = y + (size_t)b * DI * HW + p;

    float vv[48];
    float s = 0.f, s2 = 0.f;
#pragma unroll
    for (int ci = 0; ci < 48; ++ci) {
        float v = yb[(size_t)(chunk * 48 + ci) * HW];
        vv[ci] = v;
        s += v;
        s2 = fmaf(v, v, s2);
    }
    __shared__ float S[8][32], S2[8][32];
    S[chunk][lpx] = s;
    S2[chunk][lpx] = s2;
    __syncthreads();
    float ts = 0.f, ts2 = 0.f;
#pragma unroll
    for (int k = 0; k < 8; ++k) { ts += S[k][lpx]; ts2 += S2[k][lpx]; }
    float mu = ts * (1.0f / DI);
    float var = ts2 * (1.0f / DI) - mu * mu;
    float inv = rsqrtf(var + 1e-5f);
#pragma unroll
    for (int ci = 0; ci < 48; ++ci) {
        int c = chunk * 48 + ci;
        float v = (vv[ci] - mu) * inv;
        yb[(size_t)c * HW] = fmaf(v, nw[c], nb[c]);
    }
}

// ---------------- K6: GRN per-channel sumsq -> Gx ----------------
// grid (384, 2), block 256.
__global__ __launch_bounds__(256) void k_grnsum(const float* __restrict__ y,
                                                float* __restrict__ gx) {
    int c = blockIdx.x, b = blockIdx.y;
    const float* yb = y + ((size_t)b * DI + c) * HW;
    float s = 0.f;
#pragma unroll 4
    for (int i = threadIdx.x; i < HW; i += 256) {
        float v = yb[i];
        s = fmaf(v, v, s);
    }
#pragma unroll
    for (int o = 32; o > 0; o >>= 1) s += __shfl_down(s, o);
    __shared__ float red[4];
    int wid = threadIdx.x >> 6;
    if ((threadIdx.x & 63) == 0) red[wid] = s;
    __syncthreads();
    if (threadIdx.x == 0) gx[b * DI + c] = sqrtf(red[0] + red[1] + red[2] + red[3]);
}

// ---------------- K7: GRN scale: sc = 1 + gamma * Gx/(mean+1e-6) ----------------
// grid 2, block 256.
__global__ __launch_bounds__(256) void k_grnscale(const float* __restrict__ gx,
                                                  const float* __restrict__ gamma,
                                                  float* __restrict__ sc) {
    int b = blockIdx.x;
    const float* g = gx + b * DI;
    float s = 0.f;
    for (int c = threadIdx.x; c < DI; c += 256) s += g[c];
#pragma unroll
    for (int o = 32; o > 0; o >>= 1) s += __shfl_down(s, o);
    __shared__ float red[4];
    __shared__ float meanv;
    int wid = threadIdx.x >> 6;
    if ((threadIdx.x & 63) == 0) red[wid] = s;
    __syncthreads();
    if (threadIdx.x == 0) meanv = (red[0] + red[1] + red[2] + red[3]) * (1.0f / DI);
    __syncthreads();
    float m = meanv;
    for (int c = threadIdx.x; c < DI; c += 256)
        sc[b * DI + c] = 1.0f + gamma[c] * (g[c] / (m + 1e-6f));
}

// ---------------- K8: out_proj GEMM fused with GRN scale/shift ----------------
// grid (16, 24, 2), block 256. Thread: 8 output channels for one pixel.
// Weights + scale/shift via wave-uniform addresses -> s_load.
__global__ __launch_bounds__(256) void k_outproj(const float* __restrict__ y,
                                                 const float* __restrict__ w,
                                                 const float* __restrict__ sc_all,
                                                 const float* __restrict__ beta,
                                                 float* __restrict__ out) {
    int og = blockIdx.y, b = blockIdx.z;
    int p = blockIdx.x * 256 + threadIdx.x;
    const float* wr = w + (size_t)og * 8 * DI;
    const float* scb = sc_all + b * DI;
    const float* yb = y + (size_t)b * DI * HW + p;
    float acc[8];
#pragma unroll
    for (int j = 0; j < 8; ++j) acc[j] = 0.f;
    for (int c = 0; c < DI; c += 4) {
        float v0 = fmaf(yb[(size_t)(c + 0) * HW], scb[c + 0], beta[c + 0]);
        float v1 = fmaf(yb[(size_t)(c + 1) * HW], scb[c + 1], beta[c + 1]);
        float v2 = fmaf(yb[(size_t)(c + 2) * HW], scb[c + 2], beta[c + 2]);
        float v3 = fmaf(yb[(size_t)(c + 3) * HW], scb[c + 3], beta[c + 3]);
#pragma unroll
        for (int j = 0; j < 8; ++j) {
            const float* wj = wr + j * DI + c;  // wave-uniform -> SGPR
            acc[j] = fmaf(wj[0], v0, fmaf(wj[1], v1, fmaf(wj[2], v2, fmaf(wj[3], v3, acc[j]))));
        }
    }
    float* ob = out + (size_t)b * DM * HW + (size_t)(og * 8) * HW + p;
#pragma unroll
    for (int j = 0; j < 8; ++j) ob[(size_t)j * HW] = acc[j];
}

extern "C" void kernel_launch(void* const* d_in, const int* in_sizes, int n_in,
                              void* d_out, int out_size, void* d_ws, size_t ws_size,
                              hipStream_t stream) {
    (void)in_sizes; (void)n_in; (void)out_size; (void)ws_size;
    const float* x          = (const float*)d_in[0];
    const float* in_proj_w  = (const float*)d_in[1];
    const float* dwconv_w   = (const float*)d_in[2];
    const float* dwconv_b   = (const float*)d_in[3];
    const float* x_down_w   = (const float*)d_in[4];
    const float* w_up_w     = (const float*)d_in[5];
    const float* l_up_w     = (const float*)d_in[6];
    const float* u_up_w     = (const float*)d_in[7];
    const float* d_up_w     = (const float*)d_in[8];
    const float* m_w        = (const float*)d_in[9];
    const float* grn_gamma  = (const float*)d_in[10];
    const float* grn_beta   = (const float*)d_in[11];
    const float* norm_w     = (const float*)d_in[12];
    const float* norm_b     = (const float*)d_in[13];
    const float* out_proj_w = (const float*)d_in[14];

    float* ws = (float*)d_ws;
    const size_t NBIG = (size_t)Bn * DI * HW;
    float* hpre = ws;                  // [B,DI,H,W], later reused as y
    float* hbuf = ws + NBIG;           // [B,DI,H,W] post-dwconv
    float* xpt  = ws + 2 * NBIG;       // [B,HW,DS]
    float* gx   = ws + 2 * NBIG + (size_t)Bn * HW * DS;
    float* sc   = gx + Bn * DI;
    float* y    = hpre;

    k_inproj<<<dim3(16, 24, 2), 256, 0, stream>>>(x, in_proj_w, hpre);
    k_dwconv<<<dim3(16, DI, Bn), 256, 0, stream>>>(hpre, dwconv_w, dwconv_b, hbuf);
    k_xdown<<<dim3(32, 4), 256, 0, stream>>>(hbuf, x_down_w, xpt);
    k_scan<<<dim3(DI, Bn), 256, 0, stream>>>(hbuf, xpt, w_up_w, l_up_w, u_up_w,
                                             d_up_w, m_w, y);
    k_ln<<<dim3(256), 256, 0, stream>>>(y, norm_w, norm_b);
    k_grnsum<<<dim3(DI, Bn), 256, 0, stream>>>(y, gx);
    k_grnscale<<<dim3(Bn), 256, 0, stream>>>(gx, grn_gamma, sc);
    k_outproj<<<dim3(16, 24, 2), 256, 0, stream>>>(y, out_proj_w, sc, grn_beta,
                                                   (float*)d_out);
}